// Round 1
// baseline (160.548 us; speedup 1.0000x reference)
//
#include <hip/hip_runtime.h>

// DLRM InteractionArch: B=32768, F=26, D=128.
// Per row: X = [dense; sparse] (27x128 f32), G = X X^T, out = [dense(128) | triu(G,k=1)(351)].
// One wave per batch row; split-bf16 (hi+lo) MFMA for near-fp32 precision.

typedef __bf16 bf16x8 __attribute__((ext_vector_type(8)));
typedef float  f32x4  __attribute__((ext_vector_type(4)));

#define ROWS      2            // batch rows per block (one per wave)
#define RSTRIDE   136          // ushorts per matrix row (128 + 8 pad, keeps 16B row alignment)
#define PLANE     (27 * RSTRIDE)   // 3672 ushorts per plane (7344 B, 16B aligned)
#define ROWLDS    (2 * PLANE)      // hi + lo planes per batch row

// fp32 -> bf16 round-to-nearest-even (inputs are finite normals; no NaN handling needed)
__device__ __forceinline__ unsigned short f2bf(float f) {
    union { float f; unsigned int u; } v; v.f = f;
    unsigned int u = v.u;
    return (unsigned short)((u + 0x7FFFu + ((u >> 16) & 1u)) >> 16);
}
__device__ __forceinline__ float bf2f(unsigned short h) {
    union { unsigned int u; float f; } v; v.u = ((unsigned int)h) << 16;
    return v.f;
}

// offset of pair (i,j), i<j, in row-major triu(27, k=1)
__device__ __forceinline__ int tri(int i, int j) {
    return i * 26 - (i * (i - 1)) / 2 + (j - i - 1);
}

__global__ __launch_bounds__(64 * ROWS)
void dlrm_interact(const float* __restrict__ dense,
                   const float* __restrict__ sparse,
                   float* __restrict__ out)
{
    __shared__ unsigned short lds[ROWS * ROWLDS];

    const int lane = threadIdx.x & 63;
    const int wid  = threadIdx.x >> 6;
    const int b    = blockIdx.x * ROWS + wid;

    unsigned short* hiP = lds + wid * ROWLDS;
    unsigned short* loP = hiP + PLANE;

    const float* dRow = dense  + (size_t)b * 128;
    const float* sRow = sparse + (size_t)b * 3328;   // 26*128
    float*       oRow = out    + (size_t)b * 479;

    // ---- load 27x128 f32 (864 float4), split to bf16 hi/lo, stage to LDS ----
    // also pass dense through to the output (exact fp32)
    for (int ci = lane; ci < 864; ci += 64) {
        float4 v;
        if (ci < 32) {
            v = *(const float4*)(dRow + 4 * ci);
            oRow[4 * ci + 0] = v.x;
            oRow[4 * ci + 1] = v.y;
            oRow[4 * ci + 2] = v.z;
            oRow[4 * ci + 3] = v.w;
        } else {
            v = *(const float4*)(sRow + 4 * ci - 128);
        }
        const unsigned short h0 = f2bf(v.x), h1 = f2bf(v.y), h2 = f2bf(v.z), h3 = f2bf(v.w);
        const unsigned short l0 = f2bf(v.x - bf2f(h0));
        const unsigned short l1 = f2bf(v.y - bf2f(h1));
        const unsigned short l2 = f2bf(v.z - bf2f(h2));
        const unsigned short l3 = f2bf(v.w - bf2f(h3));

        const int row = ci >> 5;           // 0..26
        const int k   = (ci & 31) << 2;    // 0,4,...,124
        const int o   = row * RSTRIDE + k; // 8B-aligned in bytes

        uint2 hv, lv;
        hv.x = (unsigned int)h0 | ((unsigned int)h1 << 16);
        hv.y = (unsigned int)h2 | ((unsigned int)h3 << 16);
        lv.x = (unsigned int)l0 | ((unsigned int)l1 << 16);
        lv.y = (unsigned int)l2 | ((unsigned int)l3 << 16);
        *(uint2*)(hiP + o) = hv;
        *(uint2*)(loP + o) = lv;
    }
    __syncthreads();

    // ---- MFMA: G = hi*hi^T + hi*lo^T + lo*hi^T over 2x2 tile grid (upper 3 tiles) ----
    // A-frag and B-frag of mfma_f32_16x16x32_bf16 read identically from X:
    // lane holds X[lane&15 (+16*tile)][8*(lane>>4) + e + 32*s]
    const int r0  = lane & 15;
    const int cc  = lane >> 4;
    const int r1  = 16 + (r0 < 11 ? r0 : 10);  // clamp: rows >=27 -> garbage lands in unwritten outputs
    const int oA0 = r0 * RSTRIDE + cc * 8;
    const int oA1 = r1 * RSTRIDE + cc * 8;

    f32x4 a00 = {0.f, 0.f, 0.f, 0.f};
    f32x4 a01 = {0.f, 0.f, 0.f, 0.f};
    f32x4 a11 = {0.f, 0.f, 0.f, 0.f};

#pragma unroll
    for (int s = 0; s < 4; ++s) {
        const int d = s * 32;
        const bf16x8 F0h = *(const bf16x8*)(hiP + oA0 + d);
        const bf16x8 F0l = *(const bf16x8*)(loP + oA0 + d);
        const bf16x8 F1h = *(const bf16x8*)(hiP + oA1 + d);
        const bf16x8 F1l = *(const bf16x8*)(loP + oA1 + d);

        a00 = __builtin_amdgcn_mfma_f32_16x16x32_bf16(F0h, F0h, a00, 0, 0, 0);
        a00 = __builtin_amdgcn_mfma_f32_16x16x32_bf16(F0h, F0l, a00, 0, 0, 0);
        a00 = __builtin_amdgcn_mfma_f32_16x16x32_bf16(F0l, F0h, a00, 0, 0, 0);

        a01 = __builtin_amdgcn_mfma_f32_16x16x32_bf16(F0h, F1h, a01, 0, 0, 0);
        a01 = __builtin_amdgcn_mfma_f32_16x16x32_bf16(F0h, F1l, a01, 0, 0, 0);
        a01 = __builtin_amdgcn_mfma_f32_16x16x32_bf16(F0l, F1h, a01, 0, 0, 0);

        a11 = __builtin_amdgcn_mfma_f32_16x16x32_bf16(F1h, F1h, a11, 0, 0, 0);
        a11 = __builtin_amdgcn_mfma_f32_16x16x32_bf16(F1h, F1l, a11, 0, 0, 0);
        a11 = __builtin_amdgcn_mfma_f32_16x16x32_bf16(F1l, F1h, a11, 0, 0, 0);
    }

    // ---- write triu: C/D layout col=lane&15, row=(lane>>4)*4+reg [m89-verified] ----
    const int rb = cc * 4;
#pragma unroll
    for (int r = 0; r < 4; ++r) {
        const int i = rb + r;
        if (i < r0)                          // G00: j = r0
            oRow[128 + tri(i, r0)] = a00[r];
        if (r0 < 11)                         // G01: j = 16+r0 < 27, i < 16 <= j always
            oRow[128 + tri(i, 16 + r0)] = a01[r];
        if (r0 < 11 && i < r0)               // G11: i'=16+i < j'=16+r0 < 27
            oRow[128 + tri(16 + i, 16 + r0)] = a11[r];
    }
}

extern "C" void kernel_launch(void* const* d_in, const int* in_sizes, int n_in,
                              void* d_out, int out_size, void* d_ws, size_t ws_size,
                              hipStream_t stream) {
    const float* dense  = (const float*)d_in[0];
    const float* sparse = (const float*)d_in[1];
    float*       out    = (float*)d_out;

    const int B = in_sizes[0] / 128;          // 32768
    dim3 grid(B / ROWS), block(64 * ROWS);
    hipLaunchKernelGGL(dlrm_interact, grid, block, 0, stream, dense, sparse, out);
}

// Round 2
// 106.187 us; speedup vs baseline: 1.5119x; 1.5119x over previous
//
#include <hip/hip_runtime.h>

// DLRM InteractionArch: B=32768, F=26, D=128.
// Per row: X = [dense; sparse] (27x128 f32), G = X X^T, out = [dense(128) | triu(G,k=1)(351)].
// One wave per batch row; LDS-free: each lane loads its MFMA fragment directly
// from global (A-frag == B-frag for a Gram matrix, so k-permutation cancels).
// Split-bf16 (hi+lo) MFMA for near-fp32 precision: G = hh^T + hl^T + lh^T.

typedef __bf16 bf16x8 __attribute__((ext_vector_type(8)));
typedef float  f32x4  __attribute__((ext_vector_type(4)));

#define WAVES 4   // batch rows per block (one wave each)

// offset of pair (i,j), i<j, in row-major triu(27, k=1)
__device__ __forceinline__ int tri(int i, int j) {
    return i * 26 - (i * (i - 1)) / 2 + (j - i - 1);
}

// split x into bf16 hi + bf16 lo (both RNE via native cvt)
__device__ __forceinline__ void split(float x, __bf16& h, __bf16& l) {
    h = (__bf16)x;
    l = (__bf16)(x - (float)h);
}

__device__ __forceinline__ void cvt8(const f32x4 a, const f32x4 b,
                                     bf16x8& H, bf16x8& L) {
#pragma unroll
    for (int e = 0; e < 4; ++e) {
        __bf16 h, l;
        split(a[e], h, l);   H[e]     = h; L[e]     = l;
        split(b[e], h, l);   H[e + 4] = h; L[e + 4] = l;
    }
}

__global__ __launch_bounds__(64 * WAVES, 4)
void dlrm_interact(const float* __restrict__ dense,
                   const float* __restrict__ sparse,
                   float* __restrict__ out)
{
    const int lane = threadIdx.x & 63;
    const int wid  = threadIdx.x >> 6;
    const int b    = blockIdx.x * WAVES + wid;

    const float* dRow = dense  + (size_t)b * 128;
    const float* sRow = sparse + (size_t)b * 3328;   // 26*128
    float*       oRow = out    + (size_t)b * 479;

    // ---- dense passthrough (exact fp32; 479-stride rows are only 4B-aligned,
    //      so stores are scalar dwords) ----
    if (lane < 32) {
        const f32x4 v = *(const f32x4*)(dRow + 4 * lane);
        oRow[4 * lane + 0] = v[0];
        oRow[4 * lane + 1] = v[1];
        oRow[4 * lane + 2] = v[2];
        oRow[4 * lane + 3] = v[3];
    }

    // ---- per-lane fragment addressing ----
    // A/B frag of mfma_f32_16x16x32_bf16: lane holds row (lane&15) [tile0] /
    // 16+(lane&15) clamped [tile1], cols (lane>>4)*8 + 32*s .. +7.
    // X[0] = dense row, X[r] = sparse[r-1].
    const int r0 = lane & 15;
    const int cc = lane >> 4;
    const int r1 = 16 + (r0 < 11 ? r0 : 10);  // clamp; garbage lands in unstored outputs

    const float* x0 = (r0 == 0) ? dRow : (sRow + (r0 - 1) * 128);
    const float* x1 = sRow + (r1 - 1) * 128;

    f32x4 a00 = {0.f, 0.f, 0.f, 0.f};
    f32x4 a01 = {0.f, 0.f, 0.f, 0.f};
    f32x4 a11 = {0.f, 0.f, 0.f, 0.f};

#pragma unroll
    for (int s = 0; s < 4; ++s) {
        const int c = cc * 8 + 32 * s;
        const f32x4 u0a = *(const f32x4*)(x0 + c);
        const f32x4 u0b = *(const f32x4*)(x0 + c + 4);
        const f32x4 u1a = *(const f32x4*)(x1 + c);
        const f32x4 u1b = *(const f32x4*)(x1 + c + 4);

        bf16x8 F0h, F0l, F1h, F1l;
        cvt8(u0a, u0b, F0h, F0l);
        cvt8(u1a, u1b, F1h, F1l);

        a00 = __builtin_amdgcn_mfma_f32_16x16x32_bf16(F0h, F0h, a00, 0, 0, 0);
        a00 = __builtin_amdgcn_mfma_f32_16x16x32_bf16(F0h, F0l, a00, 0, 0, 0);
        a00 = __builtin_amdgcn_mfma_f32_16x16x32_bf16(F0l, F0h, a00, 0, 0, 0);

        a01 = __builtin_amdgcn_mfma_f32_16x16x32_bf16(F0h, F1h, a01, 0, 0, 0);
        a01 = __builtin_amdgcn_mfma_f32_16x16x32_bf16(F0h, F1l, a01, 0, 0, 0);
        a01 = __builtin_amdgcn_mfma_f32_16x16x32_bf16(F0l, F1h, a01, 0, 0, 0);

        a11 = __builtin_amdgcn_mfma_f32_16x16x32_bf16(F1h, F1h, a11, 0, 0, 0);
        a11 = __builtin_amdgcn_mfma_f32_16x16x32_bf16(F1h, F1l, a11, 0, 0, 0);
        a11 = __builtin_amdgcn_mfma_f32_16x16x32_bf16(F1l, F1h, a11, 0, 0, 0);
    }

    // ---- write triu: C/D layout col=lane&15, row=(lane>>4)*4+reg [m89-verified] ----
    const int rb = cc * 4;
#pragma unroll
    for (int r = 0; r < 4; ++r) {
        const int i = rb + r;
        if (i < r0)                          // G00: (i, r0), i < r0 < 16
            oRow[128 + tri(i, r0)] = a00[r];
        if (r0 < 11)                         // G01: (i, 16+r0), i < 16 <= j
            oRow[128 + tri(i, 16 + r0)] = a01[r];
        if (r0 < 11 && i < r0)               // G11: (16+i, 16+r0)
            oRow[128 + tri(16 + i, 16 + r0)] = a11[r];
    }
}

extern "C" void kernel_launch(void* const* d_in, const int* in_sizes, int n_in,
                              void* d_out, int out_size, void* d_ws, size_t ws_size,
                              hipStream_t stream) {
    const float* dense  = (const float*)d_in[0];
    const float* sparse = (const float*)d_in[1];
    float*       out    = (float*)d_out;

    const int B = in_sizes[0] / 128;          // 32768
    dim3 grid(B / WAVES), block(64 * WAVES);
    hipLaunchKernelGGL(dlrm_interact, grid, block, 0, stream, dense, sparse, out);
}